// Round 4
// baseline (2353.374 us; speedup 1.0000x reference)
//
#include <hip/hip_runtime.h>
#include <hip/hip_bf16.h>
#include <stdint.h>

#define Bb 128
#define Ss 512
#define Hh 1024
#define Vv 128

#define GROUPS 8
#define WPG 16      // workgroups per group
#define MB 16       // batch rows per group
#define NCOL 64     // output columns per WG

typedef __attribute__((ext_vector_type(8))) short short8;
typedef __attribute__((ext_vector_type(4))) float float4v;

static __device__ __forceinline__ short f2bf(float f) {
    union { float f; uint32_t u; } x; x.f = f;
    uint32_t r = x.u + 0x7FFFu + ((x.u >> 16) & 1u);   // RNE
    return (short)(r >> 16);
}
static __device__ __forceinline__ float bf2f(uint16_t b) {
    union { uint32_t u; float f; } x; x.u = ((uint32_t)b) << 16;
    return x.f;
}

// ---------------- Kernel 1: P = emb @ W_ih^T + b_ih + b_hh  ----------------
__global__ void k_prep(const float* __restrict__ emb, const float* __restrict__ Wih,
                       const float* __restrict__ bih, const float* __restrict__ bhh,
                       float* __restrict__ P) {
    int v = blockIdx.x >> 2;                       // 0..127
    int i = ((blockIdx.x & 3) << 8) + threadIdx.x; // 0..1023
    const float4v* e4 = (const float4v*)(emb + v * Hh);
    const float4v* w4 = (const float4v*)(Wih + i * Hh);
    float acc = 0.f;
    #pragma unroll 4
    for (int h = 0; h < Hh / 4; ++h) {
        float4v a = e4[h], b = w4[h];
        acc += a[0]*b[0] + a[1]*b[1] + a[2]*b[2] + a[3]*b[3];
    }
    P[v * Hh + i] = acc + bih[i] + bhh[i];
}

// ---------------- Kernel 2: the 512-step recurrence ----------------
// grid = 128 WGs = 8 groups x 16 WGs, block = 256 threads (4 waves).
// All h/flag traffic: sc0 sc1 (MALL-coherent, no L2 cache-maintenance ops).
// Sync = 64 per-wave store-flags per group (exactly wave-width), polled with
// ONE coalesced 64-lane load + __all(). No atomics, no RMW serialization.
__launch_bounds__(256, 1)
__global__ void k_rnn(const int* __restrict__ x, const float* __restrict__ Whh,
                      const float* __restrict__ P,
                      uint16_t* __restrict__ h0, uint16_t* __restrict__ h1,
                      uint32_t* __restrict__ flags) {
    __shared__ int    x_lds[Ss][MB];      // 32 KB  [t][r]
    __shared__ float  P_lds[Vv][NCOL];    // 32 KB
    __shared__ float4v red[4][4][64];     // 16 KB  [wave][ntile][lane]

    const int g    = blockIdx.x >> 4;
    const int w    = blockIdx.x & 15;
    const int r0   = g * MB;
    const int n0   = w * NCOL;
    const int tid  = threadIdx.x;
    const int lane = tid & 63;
    const int q    = tid >> 6;            // wave id == K-quarter

    // stage x slice: x_lds[t][r] = x[(r0+r)*S + t]
    for (int l = tid; l < Ss * MB; l += 256) {
        int t = l >> 4, r = l & 15;
        x_lds[t][r] = x[(r0 + r) * Ss + t];
    }
    // stage P slice (columns n0..n0+63, all 128 vocab rows)
    for (int l = tid; l < Vv * NCOL; l += 256) {
        int v = l >> 6, c = l & 63;
        P_lds[v][c] = P[v * Hh + n0 + c];
    }

    // W_hh slice -> registers as bf16 MFMA B-fragments (128 VGPRs).
    // B[k][n] = W_hh[n0 + nt*16 + (lane&15)][k],  k = q*256 + s*32 + (lane>>4)*8 + e
    short8 bf[4][8];
    {
        const int n_lane = lane & 15;
        const int k_base = q * 256 + ((lane >> 4) << 3);
        #pragma unroll
        for (int nt = 0; nt < 4; ++nt) {
            const float* wrow = Whh + (size_t)(n0 + nt * 16 + n_lane) * Hh;
            #pragma unroll
            for (int s = 0; s < 8; ++s) {
                const float* src = wrow + k_base + s * 32;
                short8 tmp;
                #pragma unroll
                for (int e = 0; e < 8; ++e) tmp[e] = f2bf(src[e]);
                bf[nt][s] = tmp;
            }
        }
    }
    __syncthreads();

    // flag layout: flags[g*64 + (w*4 + q)], 4B packed -> one group = 256 B.
    uint32_t* grp_flags = flags + (g << 6);
    uint32_t* myflag    = grp_flags + ((w << 2) + q);
    const uint32_t* pollp = grp_flags + lane;     // lane l polls flag l

    const int row_base = (lane >> 4) << 2;    // D row = (lane>>4)*4 + e
    const int c_lane   = lane & 15;           // D col = lane&15 ; A row = lane&15

    for (int t = 0; t < Ss; ++t) {
        float4v acc0 = {0.f,0.f,0.f,0.f}, acc1 = {0.f,0.f,0.f,0.f};
        float4v acc2 = {0.f,0.f,0.f,0.f}, acc3 = {0.f,0.f,0.f,0.f};

        if (t > 0) {
            // ---- wave-parallel group barrier: wait until all 64 flags >= t ----
            const uint32_t tgt = (uint32_t)t;
            for (;;) {
                uint32_t fv;
                asm volatile("global_load_dword %0, %1, off sc0 sc1\n\t"
                             "s_waitcnt vmcnt(0)"
                             : "=v"(fv) : "v"(pollp) : "memory");
                if (__all((int)(fv >= tgt))) break;
            }

            const uint16_t* hin = (t & 1) ? h1 : h0;
            // A[m][k]: m = lane&15 (batch row), k = q*256 + s*32 + (lane>>4)*8 + e
            const uint16_t* arow = hin + (size_t)(r0 + c_lane) * Hh + q * 256 + ((lane >> 4) << 3);
            short8 a0,a1,a2,a3,a4,a5,a6,a7;
            asm volatile(
                "global_load_dwordx4 %0, %8, off sc0 sc1\n\t"
                "global_load_dwordx4 %1, %8, off offset:64 sc0 sc1\n\t"
                "global_load_dwordx4 %2, %8, off offset:128 sc0 sc1\n\t"
                "global_load_dwordx4 %3, %8, off offset:192 sc0 sc1\n\t"
                "global_load_dwordx4 %4, %8, off offset:256 sc0 sc1\n\t"
                "global_load_dwordx4 %5, %8, off offset:320 sc0 sc1\n\t"
                "global_load_dwordx4 %6, %8, off offset:384 sc0 sc1\n\t"
                "global_load_dwordx4 %7, %8, off offset:448 sc0 sc1\n\t"
                "s_waitcnt vmcnt(0)"
                : "=&v"(a0), "=&v"(a1), "=&v"(a2), "=&v"(a3),
                  "=&v"(a4), "=&v"(a5), "=&v"(a6), "=&v"(a7)
                : "v"(arow)
                : "memory");
            #define MM(s, areg) \
                acc0 = __builtin_amdgcn_mfma_f32_16x16x32_bf16(areg, bf[0][s], acc0, 0,0,0); \
                acc1 = __builtin_amdgcn_mfma_f32_16x16x32_bf16(areg, bf[1][s], acc1, 0,0,0); \
                acc2 = __builtin_amdgcn_mfma_f32_16x16x32_bf16(areg, bf[2][s], acc2, 0,0,0); \
                acc3 = __builtin_amdgcn_mfma_f32_16x16x32_bf16(areg, bf[3][s], acc3, 0,0,0);
            MM(0,a0) MM(1,a1) MM(2,a2) MM(3,a3) MM(4,a4) MM(5,a5) MM(6,a6) MM(7,a7)
            #undef MM
        }

        red[q][0][lane] = acc0;
        red[q][1][lane] = acc1;
        red[q][2][lane] = acc2;
        red[q][3][lane] = acc3;
        __syncthreads();   // the ONLY intra-WG sync per step

        // wave q reduces & writes n-tile q (cols n0 + q*16 .. +15)
        {
            float4v u = red[0][q][lane];
            u += red[1][q][lane];
            u += red[2][q][lane];
            u += red[3][q][lane];
            uint16_t* hout = ((t + 1) & 1) ? h1 : h0;
            const int pcol = q * 16 + c_lane;
            const int ncol = n0 + pcol;
            int v0i = x_lds[t][row_base + 0], v1i = x_lds[t][row_base + 1];
            int v2i = x_lds[t][row_base + 2], v3i = x_lds[t][row_base + 3];
            uint32_t b0 = (uint16_t)f2bf(tanhf(u[0] + P_lds[v0i][pcol]));
            uint32_t b1 = (uint16_t)f2bf(tanhf(u[1] + P_lds[v1i][pcol]));
            uint32_t b2 = (uint16_t)f2bf(tanhf(u[2] + P_lds[v2i][pcol]));
            uint32_t b3 = (uint16_t)f2bf(tanhf(u[3] + P_lds[v3i][pcol]));
            uint16_t* p0 = hout + (size_t)(r0 + row_base) * Hh + ncol;
            uint16_t* p2 = p0 + 2 * Hh;
            const uint32_t tp1 = (uint32_t)(t + 1);
            // h stores -> ack at MALL -> flag store: one asm block, airtight order
            asm volatile(
                "global_store_short %0, %2, off sc0 sc1\n\t"
                "global_store_short %0, %3, off offset:2048 sc0 sc1\n\t"
                "global_store_short %1, %4, off sc0 sc1\n\t"
                "global_store_short %1, %5, off offset:2048 sc0 sc1\n\t"
                "s_waitcnt vmcnt(0)\n\t"
                "global_store_dword %6, %7, off sc0 sc1"
                :: "v"(p0), "v"(p2), "v"(b0), "v"(b1), "v"(b2), "v"(b3),
                   "v"(myflag), "v"(tp1)
                : "memory");
        }
    }
}

// ---------------- Kernel 3: out = hT @ W_fc^T + b_fc ----------------
// grid 64 (8x8 tiles of 16x16), block 256, one output per thread
__global__ void k_fc(const uint16_t* __restrict__ hT, const float* __restrict__ Wfc,
                     const float* __restrict__ bfc, float* __restrict__ out) {
    int bb = (blockIdx.x >> 3) << 4;
    int vb = (blockIdx.x & 7) << 4;
    int b  = bb + (threadIdx.x >> 4);
    int v  = vb + (threadIdx.x & 15);
    const uint16_t* hrow = hT + (size_t)b * Hh;
    const float*    wrow = Wfc + (size_t)v * Hh;
    float acc = 0.f;
    #pragma unroll 4
    for (int i = 0; i < Hh; i += 4) {
        float4v wv = *(const float4v*)(wrow + i);
        acc += bf2f(hrow[i + 0]) * wv[0] + bf2f(hrow[i + 1]) * wv[1]
             + bf2f(hrow[i + 2]) * wv[2] + bf2f(hrow[i + 3]) * wv[3];
    }
    out[(size_t)b * Vv + v] = acc + bfc[v];
}

extern "C" void kernel_launch(void* const* d_in, const int* in_sizes, int n_in,
                              void* d_out, int out_size, void* d_ws, size_t ws_size,
                              hipStream_t stream) {
    const int*   x   = (const int*)d_in[0];
    const float* emb = (const float*)d_in[1];
    const float* Wih = (const float*)d_in[2];
    const float* Whh = (const float*)d_in[3];
    const float* bih = (const float*)d_in[4];
    const float* bhh = (const float*)d_in[5];
    const float* Wfc = (const float*)d_in[6];
    const float* bfc = (const float*)d_in[7];
    float* out = (float*)d_out;

    char* ws = (char*)d_ws;
    float*    P     = (float*)ws;                     // 512 KB: [128][1024] f32
    uint16_t* h0    = (uint16_t*)(ws + (512 << 10));  // 256 KB: [128][1024] bf16
    uint16_t* h1    = (uint16_t*)(ws + (768 << 10));  // 256 KB
    uint32_t* flags = (uint32_t*)(ws + (1024 << 10)); // 8 groups x 64 x 4B = 2 KB

    hipMemsetAsync(flags, 0, 4096, stream);           // flags must start at 0 every call
    k_prep<<<512, 256, 0, stream>>>(emb, Wih, bih, bhh, P);
    k_rnn<<<128, 256, 0, stream>>>(x, Whh, P, h0, h1, flags);
    k_fc<<<64, 256, 0, stream>>>(h0, Wfc, bfc, out);
}

// Round 5
// 1761.875 us; speedup vs baseline: 1.3357x; 1.3357x over previous
//
#include <hip/hip_runtime.h>
#include <hip/hip_bf16.h>
#include <stdint.h>

#define Bb 128
#define Ss 512
#define Hh 1024
#define Vv 128

#define GROUPS 8
#define WPG 16      // workgroups per group
#define MB 16       // batch rows per group
#define NCOL 64     // output columns per WG

typedef __attribute__((ext_vector_type(8))) short short8;
typedef __attribute__((ext_vector_type(4))) float float4v;

static __device__ __forceinline__ short f2bf(float f) {
    union { float f; uint32_t u; } x; x.f = f;
    uint32_t r = x.u + 0x7FFFu + ((x.u >> 16) & 1u);   // RNE
    return (short)(r >> 16);
}
static __device__ __forceinline__ float bf2f(uint16_t b) {
    union { uint32_t u; float f; } x; x.u = ((uint32_t)b) << 16;
    return x.f;
}

// ---------------- Kernel 1: P = emb @ W_ih^T + b_ih + b_hh  ----------------
__global__ void k_prep(const float* __restrict__ emb, const float* __restrict__ Wih,
                       const float* __restrict__ bih, const float* __restrict__ bhh,
                       float* __restrict__ P) {
    int v = blockIdx.x >> 2;                       // 0..127
    int i = ((blockIdx.x & 3) << 8) + threadIdx.x; // 0..1023
    const float4v* e4 = (const float4v*)(emb + v * Hh);
    const float4v* w4 = (const float4v*)(Wih + i * Hh);
    float acc = 0.f;
    #pragma unroll 4
    for (int h = 0; h < Hh / 4; ++h) {
        float4v a = e4[h], b = w4[h];
        acc += a[0]*b[0] + a[1]*b[1] + a[2]*b[2] + a[3]*b[3];
    }
    P[v * Hh + i] = acc + bih[i] + bhh[i];
}

// ---------------- Kernel 2: the 512-step recurrence ----------------
// grid = 128 WGs = 8 groups x 16 WGs, block = 256 threads (4 waves).
// All h/flag traffic: sc0 sc1 (MALL-coherent, zero cache-maintenance ops).
// Sync: ONE flag per WG (16B-padded), stored by wave 0 after a single
// vmcnt(0) ack of its full-line h stores; ONE polling wave per WG.
__launch_bounds__(256, 1)
__global__ void k_rnn(const int* __restrict__ x, const float* __restrict__ Whh,
                      const float* __restrict__ P,
                      uint16_t* __restrict__ h0, uint16_t* __restrict__ h1,
                      uint32_t* __restrict__ flags) {
    __shared__ int      x_lds[Ss][MB];      // 32 KB  [t][r]
    __shared__ float    P_lds[Vv][NCOL];    // 32 KB
    __shared__ float4v  red[4][4][64];      // 16 KB  [wave][ntile][lane]
    __shared__ uint16_t out_t[MB][NCOL];    //  2 KB  row-major result tile

    const int g    = blockIdx.x >> 4;
    const int w    = blockIdx.x & 15;
    const int r0   = g * MB;
    const int n0   = w * NCOL;
    const int tid  = threadIdx.x;
    const int lane = tid & 63;
    const int q    = tid >> 6;            // wave id == K-quarter

    // stage x slice: x_lds[t][r] = x[(r0+r)*S + t]
    for (int l = tid; l < Ss * MB; l += 256) {
        int t = l >> 4, r = l & 15;
        x_lds[t][r] = x[(r0 + r) * Ss + t];
    }
    // stage P slice (columns n0..n0+63, all 128 vocab rows)
    for (int l = tid; l < Vv * NCOL; l += 256) {
        int v = l >> 6, c = l & 63;
        P_lds[v][c] = P[v * Hh + n0 + c];
    }

    // W_hh slice -> registers as bf16 MFMA B-fragments (128 VGPRs).
    // B[k][n] = W_hh[n0 + nt*16 + (lane&15)][k],  k = q*256 + s*32 + (lane>>4)*8 + e
    short8 bf[4][8];
    {
        const int n_lane = lane & 15;
        const int k_base = q * 256 + ((lane >> 4) << 3);
        #pragma unroll
        for (int nt = 0; nt < 4; ++nt) {
            const float* wrow = Whh + (size_t)(n0 + nt * 16 + n_lane) * Hh;
            #pragma unroll
            for (int s = 0; s < 8; ++s) {
                const float* src = wrow + k_base + s * 32;
                short8 tmp;
                #pragma unroll
                for (int e = 0; e < 8; ++e) tmp[e] = f2bf(src[e]);
                bf[nt][s] = tmp;
            }
        }
    }
    __syncthreads();

    // flag layout: one u32 per WG, padded to 16B -> one group = 16 x 16B = 4 lines.
    uint32_t*       myflag = flags + (((g << 4) + w) << 2);
    const uint32_t* pollp  = flags + (((g << 4) + (lane & 15)) << 2);

    const int row_base = (lane >> 4) << 2;    // D row = (lane>>4)*4 + e
    const int c_lane   = lane & 15;           // D col = lane&15 ; A row = lane&15

    for (int t = 0; t < Ss; ++t) {
        float4v acc0 = {0.f,0.f,0.f,0.f}, acc1 = {0.f,0.f,0.f,0.f};
        float4v acc2 = {0.f,0.f,0.f,0.f}, acc3 = {0.f,0.f,0.f,0.f};

        if (t > 0) {
            // ---- group barrier: wave 0 polls the 16 WG-flags, others park ----
            if (q == 0) {
                const uint32_t tgt = (uint32_t)t;
                uint32_t fv;
                do {
                    asm volatile("global_load_dword %0, %1, off sc0 sc1\n\t"
                                 "s_waitcnt vmcnt(0)"
                                 : "=v"(fv) : "v"(pollp) : "memory");
                } while (!__all((int)(fv >= tgt)));
            }
            __syncthreads();   // #1: release — h_t is visible at MALL

            const uint16_t* hin = (t & 1) ? h1 : h0;
            // A[m][k]: m = lane&15 (batch row), k = q*256 + s*32 + (lane>>4)*8 + e
            const uint16_t* arow = hin + (size_t)(r0 + c_lane) * Hh + q * 256 + ((lane >> 4) << 3);
            short8 a0,a1,a2,a3,a4,a5,a6,a7;
            asm volatile(
                "global_load_dwordx4 %0, %8, off sc0 sc1\n\t"
                "global_load_dwordx4 %1, %8, off offset:64 sc0 sc1\n\t"
                "global_load_dwordx4 %2, %8, off offset:128 sc0 sc1\n\t"
                "global_load_dwordx4 %3, %8, off offset:192 sc0 sc1\n\t"
                "global_load_dwordx4 %4, %8, off offset:256 sc0 sc1\n\t"
                "global_load_dwordx4 %5, %8, off offset:320 sc0 sc1\n\t"
                "global_load_dwordx4 %6, %8, off offset:384 sc0 sc1\n\t"
                "global_load_dwordx4 %7, %8, off offset:448 sc0 sc1\n\t"
                "s_waitcnt vmcnt(0)"
                : "=&v"(a0), "=&v"(a1), "=&v"(a2), "=&v"(a3),
                  "=&v"(a4), "=&v"(a5), "=&v"(a6), "=&v"(a7)
                : "v"(arow)
                : "memory");
            #define MM(s, areg) \
                acc0 = __builtin_amdgcn_mfma_f32_16x16x32_bf16(areg, bf[0][s], acc0, 0,0,0); \
                acc1 = __builtin_amdgcn_mfma_f32_16x16x32_bf16(areg, bf[1][s], acc1, 0,0,0); \
                acc2 = __builtin_amdgcn_mfma_f32_16x16x32_bf16(areg, bf[2][s], acc2, 0,0,0); \
                acc3 = __builtin_amdgcn_mfma_f32_16x16x32_bf16(areg, bf[3][s], acc3, 0,0,0);
            MM(0,a0) MM(1,a1) MM(2,a2) MM(3,a3) MM(4,a4) MM(5,a5) MM(6,a6) MM(7,a7)
            #undef MM
        }

        red[q][0][lane] = acc0;
        red[q][1][lane] = acc1;
        red[q][2][lane] = acc2;
        red[q][3][lane] = acc3;
        __syncthreads();   // #2

        // wave q reduces its n-tile, tanh, write bf16 into LDS tile
        {
            float4v u = red[0][q][lane];
            u += red[1][q][lane];
            u += red[2][q][lane];
            u += red[3][q][lane];
            const int pcol = q * 16 + c_lane;
            int v0i = x_lds[t][row_base + 0], v1i = x_lds[t][row_base + 1];
            int v2i = x_lds[t][row_base + 2], v3i = x_lds[t][row_base + 3];
            out_t[row_base + 0][pcol] = (uint16_t)f2bf(tanhf(u[0] + P_lds[v0i][pcol]));
            out_t[row_base + 1][pcol] = (uint16_t)f2bf(tanhf(u[1] + P_lds[v1i][pcol]));
            out_t[row_base + 2][pcol] = (uint16_t)f2bf(tanhf(u[2] + P_lds[v2i][pcol]));
            out_t[row_base + 3][pcol] = (uint16_t)f2bf(tanhf(u[3] + P_lds[v3i][pcol]));
        }
        __syncthreads();   // #3: out_t complete

        // wave 0: full-line coalesced store of the 16x64 tile + ack + flag
        if (q == 0) {
            uint16_t* hout = ((t + 1) & 1) ? h1 : h0;
            const uint32_t* o32 = (const uint32_t*)out_t;   // [16][32]
            const int rhalf = (lane >> 5) << 3;             // 0 or 8
            const int c32   = lane & 31;
            uint32_t sv[8];
            const uint32_t* sp[8];
            #pragma unroll
            for (int k = 0; k < 8; ++k) {
                int row = rhalf + k;
                sv[k] = o32[row * 32 + c32];
                sp[k] = (const uint32_t*)(hout + (size_t)(r0 + row) * Hh + n0 + (c32 << 1));
            }
            const uint32_t tp1 = (uint32_t)(t + 1);
            asm volatile(
                "global_store_dword %8, %0, off sc0 sc1\n\t"
                "global_store_dword %9, %1, off sc0 sc1\n\t"
                "global_store_dword %10, %2, off sc0 sc1\n\t"
                "global_store_dword %11, %3, off sc0 sc1\n\t"
                "global_store_dword %12, %4, off sc0 sc1\n\t"
                "global_store_dword %13, %5, off sc0 sc1\n\t"
                "global_store_dword %14, %6, off sc0 sc1\n\t"
                "global_store_dword %15, %7, off sc0 sc1\n\t"
                "s_waitcnt vmcnt(0)\n\t"
                "global_store_dword %16, %17, off sc0 sc1"
                :: "v"(sv[0]), "v"(sv[1]), "v"(sv[2]), "v"(sv[3]),
                   "v"(sv[4]), "v"(sv[5]), "v"(sv[6]), "v"(sv[7]),
                   "v"(sp[0]), "v"(sp[1]), "v"(sp[2]), "v"(sp[3]),
                   "v"(sp[4]), "v"(sp[5]), "v"(sp[6]), "v"(sp[7]),
                   "v"(myflag), "v"(tp1)
                : "memory");
        }
    }
}

// ---------------- Kernel 3: out = hT @ W_fc^T + b_fc ----------------
// grid 64 (8x8 tiles of 16x16), block 256, one output per thread
__global__ void k_fc(const uint16_t* __restrict__ hT, const float* __restrict__ Wfc,
                     const float* __restrict__ bfc, float* __restrict__ out) {
    int bb = (blockIdx.x >> 3) << 4;
    int vb = (blockIdx.x & 7) << 4;
    int b  = bb + (threadIdx.x >> 4);
    int v  = vb + (threadIdx.x & 15);
    const uint16_t* hrow = hT + (size_t)b * Hh;
    const float*    wrow = Wfc + (size_t)v * Hh;
    float acc = 0.f;
    #pragma unroll 4
    for (int i = 0; i < Hh; i += 4) {
        float4v wv = *(const float4v*)(wrow + i);
        acc += bf2f(hrow[i + 0]) * wv[0] + bf2f(hrow[i + 1]) * wv[1]
             + bf2f(hrow[i + 2]) * wv[2] + bf2f(hrow[i + 3]) * wv[3];
    }
    out[(size_t)b * Vv + v] = acc + bfc[v];
}

extern "C" void kernel_launch(void* const* d_in, const int* in_sizes, int n_in,
                              void* d_out, int out_size, void* d_ws, size_t ws_size,
                              hipStream_t stream) {
    const int*   x   = (const int*)d_in[0];
    const float* emb = (const float*)d_in[1];
    const float* Wih = (const float*)d_in[2];
    const float* Whh = (const float*)d_in[3];
    const float* bih = (const float*)d_in[4];
    const float* bhh = (const float*)d_in[5];
    const float* Wfc = (const float*)d_in[6];
    const float* bfc = (const float*)d_in[7];
    float* out = (float*)d_out;

    char* ws = (char*)d_ws;
    float*    P     = (float*)ws;                     // 512 KB: [128][1024] f32
    uint16_t* h0    = (uint16_t*)(ws + (512 << 10));  // 256 KB: [128][1024] bf16
    uint16_t* h1    = (uint16_t*)(ws + (768 << 10));  // 256 KB
    uint32_t* flags = (uint32_t*)(ws + (1024 << 10)); // 128 WGs x 16B = 2 KB

    hipMemsetAsync(flags, 0, 4096, stream);           // flags must start at 0 every call
    k_prep<<<512, 256, 0, stream>>>(emb, Wih, bih, bhh, P);
    k_rnn<<<128, 256, 0, stream>>>(x, Whh, P, h0, h1, flags);
    k_fc<<<64, 256, 0, stream>>>(h0, Wfc, bfc, out);
}